// Round 7
// baseline (480.361 us; speedup 1.0000x reference)
//
#include <hip/hip_runtime.h>

// DiffusionMLS: out[row[e]] += w[e]*(u[col[e]] - u[row[e]]), F=32 fp32.
// Round 7: bucket multisplit. Nodes grouped into 64-node buckets; edges
// bucket-sorted (hist + scan + sequential-cursor scatter, per-(section,bucket)
// runs laid out bucket-major); one block per bucket accumulates w*u[col] into
// an LDS f32 tile (33-float padded rows) via LDS atomics, then writes
// out = acc - wsum*u once. No f32 global atomics, no per-node cursors.

#define NFEAT 32
#define BUCKET_BITS 6
#define BUCKET 64            // nodes per bucket; rowLow fits 6 bits
#define NSEC 8               // edge sections -> XCD affinity via blockIdx%8
#define SCAN_TILE 2048

typedef float nfloat4 __attribute__((ext_vector_type(4)));
typedef unsigned int nuint2 __attribute__((ext_vector_type(2)));

__device__ __forceinline__ float4 nt_load_f4(const float4* p) {
    nfloat4 v = __builtin_nontemporal_load((const nfloat4*)p);
    return make_float4(v.x, v.y, v.z, v.w);
}
__device__ __forceinline__ void nt_store_f4(float4* p, float4 v) {
    nfloat4 t = {v.x, v.y, v.z, v.w};
    __builtin_nontemporal_store(t, (nfloat4*)p);
}
__device__ __forceinline__ uint2 nt_load_u2(const uint2* p) {
    nuint2 v = __builtin_nontemporal_load((const nuint2*)p);
    uint2 r; r.x = v.x; r.y = v.y; return r;
}

// ---------------- u -> bf16 (RNE) ----------------
__global__ __launch_bounds__(256) void convert_u_kernel(const float4* __restrict__ u4,
                                                        ushort4* __restrict__ ub, int n4) {
    int i = blockIdx.x * 256 + threadIdx.x;
    if (i >= n4) return;
    float4 v = nt_load_f4(&u4[i]);
    ushort4 o;
    unsigned x;
    x = __float_as_uint(v.x); x += 0x7fffu + ((x >> 16) & 1u); o.x = (unsigned short)(x >> 16);
    x = __float_as_uint(v.y); x += 0x7fffu + ((x >> 16) & 1u); o.y = (unsigned short)(x >> 16);
    x = __float_as_uint(v.z); x += 0x7fffu + ((x >> 16) & 1u); o.z = (unsigned short)(x >> 16);
    x = __float_as_uint(v.w); x += 0x7fffu + ((x >> 16) & 1u); o.w = (unsigned short)(x >> 16);
    ub[i] = o;
}

// ---------------- phase A: per-(section,bucket) histogram ----------------
// counts laid out s-major: counts[s*NB + b] -> each line touched by one section.
__global__ __launch_bounds__(256) void hist_sec_kernel(const int* __restrict__ row,
                                                       int* __restrict__ counts,
                                                       int E, int secLen, int NB) {
    extern __shared__ int h[];   // NB ints
    int s = blockIdx.x & (NSEC - 1);
    int cb = blockIdx.x >> 3;
    int blocksPerSec = gridDim.x >> 3;
    int lo = s * secLen;
    int hi = min(E, lo + secLen);
    for (int i = threadIdx.x; i < NB; i += 256) h[i] = 0;
    __syncthreads();
    int stride = blocksPerSec * 256;
    for (int e = lo + cb * 256 + threadIdx.x; e < hi; e += stride) {
        int r = __builtin_nontemporal_load(&row[e]);
        atomicAdd(&h[r >> BUCKET_BITS], 1);
    }
    __syncthreads();
    for (int i = threadIdx.x; i < NB; i += 256) {
        int v = h[i];
        if (v) atomicAdd(&counts[s * NB + i], v);
    }
}

// ---------------- scan over M = NB*8 elements in BUCKET-MAJOR order ----------
// element i corresponds to (b = i>>3, s = i&7); value read from counts[s*NB+b].
__global__ __launch_bounds__(256) void scan_block_kernel(const int* __restrict__ counts,
                                                         int* __restrict__ offsets,
                                                         int* __restrict__ partials,
                                                         int M, int NB) {
    __shared__ int sm[256];
    int tid = threadIdx.x;
    int base = blockIdx.x * SCAN_TILE + tid * 8;
    int v[8];
    int sum = 0;
#pragma unroll
    for (int j = 0; j < 8; ++j) {
        int i = base + j;
        v[j] = (i < M) ? counts[(i & 7) * NB + (i >> 3)] : 0;
        sum += v[j];
    }
    sm[tid] = sum;
    __syncthreads();
    for (int off = 1; off < 256; off <<= 1) {
        int t = (tid >= off) ? sm[tid - off] : 0;
        __syncthreads();
        sm[tid] += t;
        __syncthreads();
    }
    if (tid == 255) partials[blockIdx.x] = sm[255];
    int run = sm[tid] - sum;
#pragma unroll
    for (int j = 0; j < 8; ++j) {
        if (base + j < M) offsets[base + j] = run;
        run += v[j];
    }
}

__global__ void scan_partials_kernel(int* partials, int nparts) {
    if (threadIdx.x == 0 && blockIdx.x == 0) {
        int run = 0;
        for (int i = 0; i < nparts; ++i) {
            int c = partials[i];
            partials[i] = run;
            run += c;
        }
    }
}

// offsets[i] += partials; cursor (s-major) seeded; offsets[M] = E sentinel.
__global__ __launch_bounds__(256) void add_offsets_kernel(int* __restrict__ offsets,
                                                          int* __restrict__ cursor,
                                                          const int* __restrict__ partials,
                                                          int M, int NB, int E) {
    int i = blockIdx.x * 256 + threadIdx.x;
    if (i < M) {
        int v = offsets[i] + partials[i >> 11];
        offsets[i] = v;
        cursor[(i & 7) * NB + (i >> 3)] = v;
    }
    if (i == 0) offsets[M] = E;
}

// ---------------- phase B: bucket-sorted scatter ----------------
// Section s blocks (blockIdx%8) read their contiguous edge range ONCE and
// append to per-(s,bucket) runs; cursors are s-major (XCD-local lines); run
// destinations advance sequentially -> lines fill completely before writeback.
__global__ __launch_bounds__(256) void fill_bucket_kernel(const int* __restrict__ row,
                                                          const int* __restrict__ col,
                                                          const float* __restrict__ w,
                                                          int* __restrict__ cursor,
                                                          uint2* __restrict__ csr,
                                                          int E, int secLen, int NB) {
    int s = blockIdx.x & (NSEC - 1);
    int cb = blockIdx.x >> 3;
    int blocksPerSec = gridDim.x >> 3;
    int lo = s * secLen;
    int hi = min(E, lo + secLen);
    int stride = blocksPerSec * 256;
    for (int e = lo + cb * 256 + threadIdx.x; e < hi; e += stride) {
        int r = __builtin_nontemporal_load(&row[e]);
        unsigned c = (unsigned)__builtin_nontemporal_load(&col[e]);
        float wt = __builtin_nontemporal_load(&w[e]);
        int b = r >> BUCKET_BITS;
        int pos = atomicAdd(&cursor[s * NB + b], 1);
        uint2 p;
        p.x = ((unsigned)(r & (BUCKET - 1)) << 26) | c;   // rowLow:6 | col:26
        p.y = __float_as_uint(wt);
        csr[pos] = p;
    }
}

// ---------------- phase C: one block per bucket, LDS f32 accumulate ---------
// 8 lanes per edge (one ushort4 = 4 bf16 feats each); tile rows padded to 33
// floats so LDS atomic banks = (rowLow + 4*f4 + j) % 32 (conflict-free-ish).
__global__ __launch_bounds__(256) void node_bucket_kernel(const ushort4* __restrict__ ub,
                                                          const float4* __restrict__ u4,
                                                          const int* __restrict__ offsets,
                                                          const uint2* __restrict__ csr,
                                                          float4* __restrict__ out4, int N) {
    __shared__ float tile[BUCKET * 33];
    __shared__ float wsum[BUCKET];
    int b = blockIdx.x;
    int tid = threadIdx.x;
    for (int i = tid; i < BUCKET * 33; i += 256) tile[i] = 0.f;
    if (tid < BUCKET) wsum[tid] = 0.f;
    __syncthreads();

    int start = offsets[b * 8];
    int end = offsets[b * 8 + 8];   // contiguous: bucket-major layout
    int f4 = tid & 7;

    for (int i = start + (tid >> 3); i < end; i += 32) {
        uint2 p = nt_load_u2(&csr[i]);
        int c = (int)(p.x & 0x03FFFFFFu);
        int rl = (int)(p.x >> 26);
        float wt = __uint_as_float(p.y);
        ushort4 us = ub[(size_t)c * 8 + f4];
        float* t = &tile[rl * 33 + f4 * 4];
        atomicAdd(t + 0, wt * __uint_as_float((unsigned)us.x << 16));
        atomicAdd(t + 1, wt * __uint_as_float((unsigned)us.y << 16));
        atomicAdd(t + 2, wt * __uint_as_float((unsigned)us.z << 16));
        atomicAdd(t + 3, wt * __uint_as_float((unsigned)us.w << 16));
        if (f4 == 0) atomicAdd(&wsum[rl], wt);
    }
    __syncthreads();

#pragma unroll
    for (int pass = 0; pass < 2; ++pass) {
        int idx = pass * 256 + tid;
        int node = idx >> 3;
        int ff = idx & 7;
        int glob = b * BUCKET + node;
        if (glob < N) {
            float4 ur = nt_load_f4(&u4[(size_t)glob * 8 + ff]);
            float ws_ = wsum[node];
            const float* t = &tile[node * 33 + ff * 4];
            float4 o;
            o.x = t[0] - ws_ * ur.x;
            o.y = t[1] - ws_ * ur.y;
            o.z = t[2] - ws_ * ur.z;
            o.w = t[3] - ws_ * ur.w;
            nt_store_f4(&out4[(size_t)glob * 8 + ff], o);
        }
    }
}

// ---------------- fallback (atomic path, if ws too small) ----------------

__global__ __launch_bounds__(256) void zero_out_kernel(float* __restrict__ out, int n) {
    int i = blockIdx.x * blockDim.x + threadIdx.x;
    if (i < n) out[i] = 0.0f;
}

__global__ __launch_bounds__(256) void scatter_lap_kernel(const float4* __restrict__ u4,
                                                          const float* __restrict__ w,
                                                          const int* __restrict__ row,
                                                          const int* __restrict__ col,
                                                          float* __restrict__ out, int n_edges) {
    int tid = blockIdx.x * blockDim.x + threadIdx.x;
    int e = tid >> 3;
    int f4 = tid & 7;
    if (e >= n_edges) return;
    int r = row[e];
    int c = col[e];
    float wt = w[e];
    float4 uc = u4[(size_t)c * 8 + f4];
    float4 ur = u4[(size_t)r * 8 + f4];
    float* o = out + (size_t)r * NFEAT + f4 * 4;
    atomicAdd(o + 0, wt * (uc.x - ur.x));
    atomicAdd(o + 1, wt * (uc.y - ur.y));
    atomicAdd(o + 2, wt * (uc.z - ur.z));
    atomicAdd(o + 3, wt * (uc.w - ur.w));
}

extern "C" void kernel_launch(void* const* d_in, const int* in_sizes, int n_in,
                              void* d_out, int out_size, void* d_ws, size_t ws_size,
                              hipStream_t stream) {
    const float* u = (const float*)d_in[0];
    const float* w = (const float*)d_in[1];
    const int* ei = (const int*)d_in[2];  // [2, E] int32
    float* out = (float*)d_out;

    const int E = in_sizes[1];
    const int N = out_size / NFEAT;
    const int* row = ei;
    const int* col = ei + E;

    const int NB = (N + BUCKET - 1) >> BUCKET_BITS;   // buckets
    const int M = NB * NSEC;                          // (bucket,section) cells
    const int secLen = (E + NSEC - 1) / NSEC;

    // workspace layout (256-B aligned)
    const size_t countsOff = 0;
    const size_t countsBytes = ((size_t)M * 4 + 255) & ~(size_t)255;
    const size_t offsetsOff = countsOff + countsBytes;
    const size_t offsetsBytes = ((size_t)(M + 1) * 4 + 255) & ~(size_t)255;
    const size_t cursorOff = offsetsOff + offsetsBytes;
    const size_t cursorBytes = countsBytes;
    const size_t partialsOff = cursorOff + cursorBytes;
    const size_t partialsBytes = 256;
    const size_t csrOff = partialsOff + partialsBytes;
    const size_t csrBytes = ((size_t)E * 8 + 255) & ~(size_t)255;
    const size_t ubOff = csrOff + csrBytes;
    const size_t ubBytes = ((size_t)N * NFEAT * 2 + 255) & ~(size_t)255;
    const size_t totalWs = ubOff + ubBytes;

    if (ws_size < totalWs || N > (1 << 26)) {
        zero_out_kernel<<<(out_size + 255) / 256, 256, 0, stream>>>(out, out_size);
        long long threads_total = (long long)E * 8;
        scatter_lap_kernel<<<(unsigned)((threads_total + 255) / 256), 256, 0, stream>>>(
            (const float4*)u, w, row, col, out, E);
        return;
    }

    char* ws = (char*)d_ws;
    int* counts = (int*)(ws + countsOff);
    int* offsets = (int*)(ws + offsetsOff);
    int* cursor = (int*)(ws + cursorOff);
    int* partials = (int*)(ws + partialsOff);
    uint2* csr = (uint2*)(ws + csrOff);
    ushort4* ub = (ushort4*)(ws + ubOff);

    (void)hipMemsetAsync(counts, 0, (size_t)M * 4, stream);

    int n4 = N * (NFEAT / 4);
    convert_u_kernel<<<(n4 + 255) / 256, 256, 0, stream>>>((const float4*)u, ub, n4);

    // phase A: histogram (8 sections x 32 blocks, dynamic LDS = NB ints)
    hist_sec_kernel<<<NSEC * 32, 256, (size_t)NB * 4, stream>>>(row, counts, E, secLen, NB);

    // scan (bucket-major order)
    const int nScanBlocks = (M + SCAN_TILE - 1) / SCAN_TILE;
    scan_block_kernel<<<nScanBlocks, 256, 0, stream>>>(counts, offsets, partials, M, NB);
    scan_partials_kernel<<<1, 64, 0, stream>>>(partials, nScanBlocks);
    add_offsets_kernel<<<(M + 255) / 256, 256, 0, stream>>>(offsets, cursor, partials, M, NB, E);

    // phase B: bucket-sorted scatter (8 sections x 64 blocks)
    fill_bucket_kernel<<<NSEC * 64, 256, 0, stream>>>(row, col, w, cursor, csr, E, secLen, NB);

    // phase C: one block per bucket
    node_bucket_kernel<<<NB, 256, 0, stream>>>(ub, (const float4*)u, offsets, csr,
                                               (float4*)out, N);
}

// Round 8
// 217.120 us; speedup vs baseline: 2.2124x; 2.2124x over previous
//
#include <hip/hip_runtime.h>

// DiffusionMLS: out[row[e]] += w[e]*(u[col[e]] - u[row[e]]), F=32 fp32.
// Round 8: phases A/B as round 7 (bucket multisplit: hist + scan + per-(sec,
// bucket) runs). Phase C REPLACED: in-LDS counting sort of the bucket's edges
// by node (2 int LDS atomics/edge instead of 32 f32 LDS atomics/edge), then
// per-node register accumulation with shuffle reduce — no f32 atomics at all.

#define NFEAT 32
#define BUCKET_BITS 6
#define BUCKET 64            // nodes per bucket; rowLow fits 6 bits
#define NSEC 8               // edge sections -> XCD affinity via blockIdx%8
#define SCAN_TILE 2048
#define EDGE_CAP 2048        // LDS staging capacity (avg bucket load ~1024)

typedef float nfloat4 __attribute__((ext_vector_type(4)));
typedef unsigned int nuint2 __attribute__((ext_vector_type(2)));

__device__ __forceinline__ float4 nt_load_f4(const float4* p) {
    nfloat4 v = __builtin_nontemporal_load((const nfloat4*)p);
    return make_float4(v.x, v.y, v.z, v.w);
}
__device__ __forceinline__ void nt_store_f4(float4* p, float4 v) {
    nfloat4 t = {v.x, v.y, v.z, v.w};
    __builtin_nontemporal_store(t, (nfloat4*)p);
}
__device__ __forceinline__ uint2 nt_load_u2(const uint2* p) {
    nuint2 v = __builtin_nontemporal_load((const nuint2*)p);
    uint2 r; r.x = v.x; r.y = v.y; return r;
}

// ---------------- u -> bf16 (RNE) ----------------
__global__ __launch_bounds__(256) void convert_u_kernel(const float4* __restrict__ u4,
                                                        ushort4* __restrict__ ub, int n4) {
    int i = blockIdx.x * 256 + threadIdx.x;
    if (i >= n4) return;
    float4 v = nt_load_f4(&u4[i]);
    ushort4 o;
    unsigned x;
    x = __float_as_uint(v.x); x += 0x7fffu + ((x >> 16) & 1u); o.x = (unsigned short)(x >> 16);
    x = __float_as_uint(v.y); x += 0x7fffu + ((x >> 16) & 1u); o.y = (unsigned short)(x >> 16);
    x = __float_as_uint(v.z); x += 0x7fffu + ((x >> 16) & 1u); o.z = (unsigned short)(x >> 16);
    x = __float_as_uint(v.w); x += 0x7fffu + ((x >> 16) & 1u); o.w = (unsigned short)(x >> 16);
    ub[i] = o;
}

// ---------------- phase A: per-(section,bucket) histogram ----------------
__global__ __launch_bounds__(256) void hist_sec_kernel(const int* __restrict__ row,
                                                       int* __restrict__ counts,
                                                       int E, int secLen, int NB) {
    extern __shared__ int h[];   // NB ints
    int s = blockIdx.x & (NSEC - 1);
    int cb = blockIdx.x >> 3;
    int blocksPerSec = gridDim.x >> 3;
    int lo = s * secLen;
    int hi = min(E, lo + secLen);
    for (int i = threadIdx.x; i < NB; i += 256) h[i] = 0;
    __syncthreads();
    int stride = blocksPerSec * 256;
    for (int e = lo + cb * 256 + threadIdx.x; e < hi; e += stride) {
        int r = __builtin_nontemporal_load(&row[e]);
        atomicAdd(&h[r >> BUCKET_BITS], 1);
    }
    __syncthreads();
    for (int i = threadIdx.x; i < NB; i += 256) {
        int v = h[i];
        if (v) atomicAdd(&counts[s * NB + i], v);
    }
}

// ---------------- scan over M = NB*8 elements in BUCKET-MAJOR order ----------
__global__ __launch_bounds__(256) void scan_block_kernel(const int* __restrict__ counts,
                                                         int* __restrict__ offsets,
                                                         int* __restrict__ partials,
                                                         int M, int NB) {
    __shared__ int sm[256];
    int tid = threadIdx.x;
    int base = blockIdx.x * SCAN_TILE + tid * 8;
    int v[8];
    int sum = 0;
#pragma unroll
    for (int j = 0; j < 8; ++j) {
        int i = base + j;
        v[j] = (i < M) ? counts[(i & 7) * NB + (i >> 3)] : 0;
        sum += v[j];
    }
    sm[tid] = sum;
    __syncthreads();
    for (int off = 1; off < 256; off <<= 1) {
        int t = (tid >= off) ? sm[tid - off] : 0;
        __syncthreads();
        sm[tid] += t;
        __syncthreads();
    }
    if (tid == 255) partials[blockIdx.x] = sm[255];
    int run = sm[tid] - sum;
#pragma unroll
    for (int j = 0; j < 8; ++j) {
        if (base + j < M) offsets[base + j] = run;
        run += v[j];
    }
}

__global__ void scan_partials_kernel(int* partials, int nparts) {
    if (threadIdx.x == 0 && blockIdx.x == 0) {
        int run = 0;
        for (int i = 0; i < nparts; ++i) {
            int c = partials[i];
            partials[i] = run;
            run += c;
        }
    }
}

__global__ __launch_bounds__(256) void add_offsets_kernel(int* __restrict__ offsets,
                                                          int* __restrict__ cursor,
                                                          const int* __restrict__ partials,
                                                          int M, int NB, int E) {
    int i = blockIdx.x * 256 + threadIdx.x;
    if (i < M) {
        int v = offsets[i] + partials[i >> 11];
        offsets[i] = v;
        cursor[(i & 7) * NB + (i >> 3)] = v;
    }
    if (i == 0) offsets[M] = E;
}

// ---------------- phase B: bucket-sorted scatter ----------------
__global__ __launch_bounds__(256) void fill_bucket_kernel(const int* __restrict__ row,
                                                          const int* __restrict__ col,
                                                          const float* __restrict__ w,
                                                          int* __restrict__ cursor,
                                                          uint2* __restrict__ csr,
                                                          int E, int secLen, int NB) {
    int s = blockIdx.x & (NSEC - 1);
    int cb = blockIdx.x >> 3;
    int blocksPerSec = gridDim.x >> 3;
    int lo = s * secLen;
    int hi = min(E, lo + secLen);
    int stride = blocksPerSec * 256;
    for (int e = lo + cb * 256 + threadIdx.x; e < hi; e += stride) {
        int r = __builtin_nontemporal_load(&row[e]);
        unsigned c = (unsigned)__builtin_nontemporal_load(&col[e]);
        float wt = __builtin_nontemporal_load(&w[e]);
        int b = r >> BUCKET_BITS;
        int pos = atomicAdd(&cursor[s * NB + b], 1);
        uint2 p;
        p.x = ((unsigned)(r & (BUCKET - 1)) << 26) | c;   // rowLow:6 | col:26
        p.y = __float_as_uint(wt);
        csr[pos] = p;
    }
}

// ---------------- phase C: in-LDS counting sort + register accumulation ------
// One block per bucket. Pass 1: LDS hist[64] (1 int atomic/edge). Scan. Pass 2:
// scatter edges into LDS sorted order (1 int atomic/edge). Then 4 waves x 16
// nodes: 8 slots x 8 f4-lanes register accumulate + shuffle reduce, one store.
__global__ __launch_bounds__(256) void node_sort_kernel(const ushort4* __restrict__ ub,
                                                        const float4* __restrict__ u4,
                                                        const int* __restrict__ offsets,
                                                        const uint2* __restrict__ csr,
                                                        float4* __restrict__ out4, int N) {
    __shared__ uint2 se[EDGE_CAP];          // 16 KB staging (or f32 tile in fallback)
    __shared__ int hist[BUCKET];
    __shared__ int starts[BUCKET + 1];
    __shared__ float wsumsh[BUCKET];

    int b = blockIdx.x;
    int tid = threadIdx.x;
    int start = offsets[b * 8];
    int end = offsets[b * 8 + 8];
    int cnt = end - start;

    if (tid < BUCKET) hist[tid] = 0;
    __syncthreads();

    if (cnt <= EDGE_CAP) {
        // pass 1: histogram by rowLow
        for (int i = start + tid; i < end; i += 256) {
            unsigned px = nt_load_u2(&csr[i]).x;
            atomicAdd(&hist[px >> 26], 1);
        }
        __syncthreads();
        if (tid == 0) {
            int run = 0;
            for (int i = 0; i < BUCKET; ++i) {
                int c = hist[i];
                starts[i] = run;
                hist[i] = run;       // reuse as cursor
                run += c;
            }
            starts[BUCKET] = run;
        }
        __syncthreads();
        // pass 2: scatter into sorted LDS order
        for (int i = start + tid; i < end; i += 256) {
            uint2 p = nt_load_u2(&csr[i]);
            int pos = atomicAdd(&hist[p.x >> 26], 1);
            se[pos] = p;
        }
        __syncthreads();
        // per-node register accumulation
        int wave = tid >> 6;
        int lane = tid & 63;
        int f4 = lane & 7;
        int slot = lane >> 3;
        for (int node = wave; node < BUCKET; node += 4) {
            int s0 = starts[node];
            int s1 = starts[node + 1];
            float4 acc = make_float4(0.f, 0.f, 0.f, 0.f);
            float ws_ = 0.f;
            for (int i = s0 + slot; i < s1; i += 8) {
                uint2 p = se[i];
                int c = (int)(p.x & 0x03FFFFFFu);
                float wt = __uint_as_float(p.y);
                ushort4 us = ub[(size_t)c * 8 + f4];
                acc.x += wt * __uint_as_float((unsigned)us.x << 16);
                acc.y += wt * __uint_as_float((unsigned)us.y << 16);
                acc.z += wt * __uint_as_float((unsigned)us.z << 16);
                acc.w += wt * __uint_as_float((unsigned)us.w << 16);
                ws_ += wt;
            }
#pragma unroll
            for (int m = 8; m < 64; m <<= 1) {
                acc.x += __shfl_xor(acc.x, m, 64);
                acc.y += __shfl_xor(acc.y, m, 64);
                acc.z += __shfl_xor(acc.z, m, 64);
                acc.w += __shfl_xor(acc.w, m, 64);
                ws_   += __shfl_xor(ws_,   m, 64);
            }
            int glob = b * BUCKET + node;
            if (slot == 0 && glob < N) {
                float4 ur = nt_load_f4(&u4[(size_t)glob * 8 + f4]);
                float4 o;
                o.x = acc.x - ws_ * ur.x;
                o.y = acc.y - ws_ * ur.y;
                o.z = acc.z - ws_ * ur.z;
                o.w = acc.w - ws_ * ur.w;
                nt_store_f4(&out4[(size_t)glob * 8 + f4], o);
            }
        }
    } else {
        // fallback for oversized buckets: LDS f32 tile (reuses se memory)
        float* tile = (float*)se;   // 64*32 floats = 8 KB
        for (int i = tid; i < BUCKET * NFEAT; i += 256) tile[i] = 0.f;
        if (tid < BUCKET) wsumsh[tid] = 0.f;
        __syncthreads();
        int f4 = tid & 7;
        for (int i = start + (tid >> 3); i < end; i += 32) {
            uint2 p = nt_load_u2(&csr[i]);
            int c = (int)(p.x & 0x03FFFFFFu);
            int rl = (int)(p.x >> 26);
            float wt = __uint_as_float(p.y);
            ushort4 us = ub[(size_t)c * 8 + f4];
            float* t = &tile[rl * NFEAT + f4 * 4];
            atomicAdd(t + 0, wt * __uint_as_float((unsigned)us.x << 16));
            atomicAdd(t + 1, wt * __uint_as_float((unsigned)us.y << 16));
            atomicAdd(t + 2, wt * __uint_as_float((unsigned)us.z << 16));
            atomicAdd(t + 3, wt * __uint_as_float((unsigned)us.w << 16));
            if (f4 == 0) atomicAdd(&wsumsh[rl], wt);
        }
        __syncthreads();
#pragma unroll
        for (int pass = 0; pass < 2; ++pass) {
            int idx = pass * 256 + tid;
            int node = idx >> 3;
            int ff = idx & 7;
            int glob = b * BUCKET + node;
            if (glob < N) {
                float4 ur = nt_load_f4(&u4[(size_t)glob * 8 + ff]);
                float ws_ = wsumsh[node];
                const float* t = &tile[node * NFEAT + ff * 4];
                float4 o;
                o.x = t[0] - ws_ * ur.x;
                o.y = t[1] - ws_ * ur.y;
                o.z = t[2] - ws_ * ur.z;
                o.w = t[3] - ws_ * ur.w;
                nt_store_f4(&out4[(size_t)glob * 8 + ff], o);
            }
        }
    }
}

// ---------------- fallback (atomic path, if ws too small) ----------------

__global__ __launch_bounds__(256) void zero_out_kernel(float* __restrict__ out, int n) {
    int i = blockIdx.x * blockDim.x + threadIdx.x;
    if (i < n) out[i] = 0.0f;
}

__global__ __launch_bounds__(256) void scatter_lap_kernel(const float4* __restrict__ u4,
                                                          const float* __restrict__ w,
                                                          const int* __restrict__ row,
                                                          const int* __restrict__ col,
                                                          float* __restrict__ out, int n_edges) {
    int tid = blockIdx.x * blockDim.x + threadIdx.x;
    int e = tid >> 3;
    int f4 = tid & 7;
    if (e >= n_edges) return;
    int r = row[e];
    int c = col[e];
    float wt = w[e];
    float4 uc = u4[(size_t)c * 8 + f4];
    float4 ur = u4[(size_t)r * 8 + f4];
    float* o = out + (size_t)r * NFEAT + f4 * 4;
    atomicAdd(o + 0, wt * (uc.x - ur.x));
    atomicAdd(o + 1, wt * (uc.y - ur.y));
    atomicAdd(o + 2, wt * (uc.z - ur.z));
    atomicAdd(o + 3, wt * (uc.w - ur.w));
}

extern "C" void kernel_launch(void* const* d_in, const int* in_sizes, int n_in,
                              void* d_out, int out_size, void* d_ws, size_t ws_size,
                              hipStream_t stream) {
    const float* u = (const float*)d_in[0];
    const float* w = (const float*)d_in[1];
    const int* ei = (const int*)d_in[2];  // [2, E] int32
    float* out = (float*)d_out;

    const int E = in_sizes[1];
    const int N = out_size / NFEAT;
    const int* row = ei;
    const int* col = ei + E;

    const int NB = (N + BUCKET - 1) >> BUCKET_BITS;   // buckets
    const int M = NB * NSEC;                          // (bucket,section) cells
    const int secLen = (E + NSEC - 1) / NSEC;

    // workspace layout (256-B aligned)
    const size_t countsOff = 0;
    const size_t countsBytes = ((size_t)M * 4 + 255) & ~(size_t)255;
    const size_t offsetsOff = countsOff + countsBytes;
    const size_t offsetsBytes = ((size_t)(M + 1) * 4 + 255) & ~(size_t)255;
    const size_t cursorOff = offsetsOff + offsetsBytes;
    const size_t cursorBytes = countsBytes;
    const size_t partialsOff = cursorOff + cursorBytes;
    const size_t partialsBytes = 256;
    const size_t csrOff = partialsOff + partialsBytes;
    const size_t csrBytes = ((size_t)E * 8 + 255) & ~(size_t)255;
    const size_t ubOff = csrOff + csrBytes;
    const size_t ubBytes = ((size_t)N * NFEAT * 2 + 255) & ~(size_t)255;
    const size_t totalWs = ubOff + ubBytes;

    if (ws_size < totalWs || N > (1 << 26)) {
        zero_out_kernel<<<(out_size + 255) / 256, 256, 0, stream>>>(out, out_size);
        long long threads_total = (long long)E * 8;
        scatter_lap_kernel<<<(unsigned)((threads_total + 255) / 256), 256, 0, stream>>>(
            (const float4*)u, w, row, col, out, E);
        return;
    }

    char* ws = (char*)d_ws;
    int* counts = (int*)(ws + countsOff);
    int* offsets = (int*)(ws + offsetsOff);
    int* cursor = (int*)(ws + cursorOff);
    int* partials = (int*)(ws + partialsOff);
    uint2* csr = (uint2*)(ws + csrOff);
    ushort4* ub = (ushort4*)(ws + ubOff);

    (void)hipMemsetAsync(counts, 0, (size_t)M * 4, stream);

    int n4 = N * (NFEAT / 4);
    convert_u_kernel<<<(n4 + 255) / 256, 256, 0, stream>>>((const float4*)u, ub, n4);

    // phase A: histogram (8 sections x 32 blocks, dynamic LDS = NB ints)
    hist_sec_kernel<<<NSEC * 32, 256, (size_t)NB * 4, stream>>>(row, counts, E, secLen, NB);

    // scan (bucket-major order)
    const int nScanBlocks = (M + SCAN_TILE - 1) / SCAN_TILE;
    scan_block_kernel<<<nScanBlocks, 256, 0, stream>>>(counts, offsets, partials, M, NB);
    scan_partials_kernel<<<1, 64, 0, stream>>>(partials, nScanBlocks);
    add_offsets_kernel<<<(M + 255) / 256, 256, 0, stream>>>(offsets, cursor, partials, M, NB, E);

    // phase B: bucket-sorted scatter (8 sections x 64 blocks)
    fill_bucket_kernel<<<NSEC * 64, 256, 0, stream>>>(row, col, w, cursor, csr, E, secLen, NB);

    // phase C: one block per bucket, counting sort + register accumulation
    node_sort_kernel<<<NB, 256, 0, stream>>>(ub, (const float4*)u, offsets, csr,
                                             (float4*)out, N);
}

// Round 9
// 194.248 us; speedup vs baseline: 2.4729x; 1.1177x over previous
//
#include <hip/hip_runtime.h>

// DiffusionMLS: out[row[e]] += w[e]*(u[col[e]] - u[row[e]]), F=32 fp32.
// Round 9: deterministic chunk multisplit. Buckets = 256 nodes (NB<=512).
// fill_sort: per 2048-edge chunk, LDS counting-sort by bucket, ONE global
// atomic per (chunk,bucket) slot reservation (~300K total vs 1.6M), then
// coalesced sorted write-out (monotone dest within bursts). Phase C: per-
// bucket LDS counting sort by node + register accumulation (r8 scheme, 256
// nodes). Single-block scan replaces the 3-kernel scan pipeline.

#define NFEAT 32
#define BUCKET_BITS 8
#define BUCKET 256           // nodes per bucket; rowLow fits 8 bits
#define MAXNB 512            // fill/scan kernels assume NB <= 512
#define CH 2048              // edges per fill chunk
#define EDGE_CAP 4608        // phase-C LDS staging cap (mean 4096, sd 64)

typedef float nfloat4 __attribute__((ext_vector_type(4)));
typedef unsigned int nuint2 __attribute__((ext_vector_type(2)));

__device__ __forceinline__ float4 nt_load_f4(const float4* p) {
    nfloat4 v = __builtin_nontemporal_load((const nfloat4*)p);
    return make_float4(v.x, v.y, v.z, v.w);
}
__device__ __forceinline__ void nt_store_f4(float4* p, float4 v) {
    nfloat4 t = {v.x, v.y, v.z, v.w};
    __builtin_nontemporal_store(t, (nfloat4*)p);
}
__device__ __forceinline__ uint2 nt_load_u2(const uint2* p) {
    nuint2 v = __builtin_nontemporal_load((const nuint2*)p);
    uint2 r; r.x = v.x; r.y = v.y; return r;
}

// ---------------- u -> bf16 (RNE) ----------------
__global__ __launch_bounds__(256) void convert_u_kernel(const float4* __restrict__ u4,
                                                        ushort4* __restrict__ ub, int n4) {
    int i = blockIdx.x * 256 + threadIdx.x;
    if (i >= n4) return;
    float4 v = nt_load_f4(&u4[i]);
    ushort4 o;
    unsigned x;
    x = __float_as_uint(v.x); x += 0x7fffu + ((x >> 16) & 1u); o.x = (unsigned short)(x >> 16);
    x = __float_as_uint(v.y); x += 0x7fffu + ((x >> 16) & 1u); o.y = (unsigned short)(x >> 16);
    x = __float_as_uint(v.z); x += 0x7fffu + ((x >> 16) & 1u); o.z = (unsigned short)(x >> 16);
    x = __float_as_uint(v.w); x += 0x7fffu + ((x >> 16) & 1u); o.w = (unsigned short)(x >> 16);
    ub[i] = o;
}

// ---------------- phase A: global bucket histogram ----------------
__global__ __launch_bounds__(256) void hist_kernel(const int* __restrict__ row,
                                                   int* __restrict__ counts,
                                                   int E, int NB) {
    __shared__ int h[MAXNB];
    for (int i = threadIdx.x; i < MAXNB; i += 256) h[i] = 0;
    __syncthreads();
    int stride = gridDim.x * 256;
    for (int e = blockIdx.x * 256 + threadIdx.x; e < E; e += stride)
        atomicAdd(&h[__builtin_nontemporal_load(&row[e]) >> BUCKET_BITS], 1);
    __syncthreads();
    for (int b = threadIdx.x; b < NB; b += 256) {
        int v = h[b];
        if (v) atomicAdd(&counts[b], v);
    }
}

// ---------------- phase B: single-block scan (NB <= 512) ----------------
__global__ __launch_bounds__(512) void scan_offsets_kernel(const int* __restrict__ counts,
                                                           int* __restrict__ offsets,
                                                           int* __restrict__ cursor,
                                                           int NB) {
    __shared__ int sc[512];
    int tid = threadIdx.x;
    int c = (tid < NB) ? counts[tid] : 0;
    sc[tid] = c;
    __syncthreads();
    for (int off = 1; off < 512; off <<= 1) {
        int v = (tid >= off) ? sc[tid - off] : 0;
        __syncthreads();
        sc[tid] += v;
        __syncthreads();
    }
    if (tid < NB) {
        int excl = sc[tid] - c;
        offsets[tid] = excl;
        cursor[tid] = excl;
    }
    if (tid == 511) offsets[NB] = sc[511];   // total = E
}

// ---------------- phase C: chunk multisplit fill ----------------
// One block per 2048-edge chunk: LDS sort by bucket, one global atomic per
// touched bucket, coalesced sorted write-out (dest monotone within bursts).
__global__ __launch_bounds__(512) void fill_sort_kernel(const int* __restrict__ row,
                                                        const int* __restrict__ col,
                                                        const float* __restrict__ w,
                                                        int* __restrict__ cursor,
                                                        uint2* __restrict__ csr,
                                                        int E) {
    __shared__ uint2 se[CH];              // raw edges           16 KB
    __shared__ uint2 so[CH];              // sorted edges        16 KB
    __shared__ int sdst[CH];              // global dest/slot     8 KB
    __shared__ unsigned short sb[CH];     // bucket per raw edge  4 KB
    __shared__ int hist[MAXNB];           // count -> rolling gcursor
    __shared__ int sc[MAXNB];             // scan -> local base
    __shared__ int gb0[MAXNB];            // reserved global base

    int tid = threadIdx.x;
    int lo = blockIdx.x * CH;
    int n = min(E - lo, CH);

    hist[tid] = 0;
    __syncthreads();

    // p1: load + pack + histogram
    for (int i = tid; i < n; i += 512) {
        int r = __builtin_nontemporal_load(&row[lo + i]);
        unsigned c = (unsigned)__builtin_nontemporal_load(&col[lo + i]);
        float wt = __builtin_nontemporal_load(&w[lo + i]);
        int b = r >> BUCKET_BITS;
        uint2 p;
        p.x = ((unsigned)(r & (BUCKET - 1)) << 24) | c;   // rowLow:8 | col:24
        p.y = __float_as_uint(wt);
        se[i] = p;
        sb[i] = (unsigned short)b;
        atomicAdd(&hist[b], 1);
    }
    __syncthreads();

    // p2: exclusive scan of hist into sc
    int myc = hist[tid];
    sc[tid] = myc;
    __syncthreads();
    for (int off = 1; off < 512; off <<= 1) {
        int v = (tid >= off) ? sc[tid - off] : 0;
        __syncthreads();
        sc[tid] += v;
        __syncthreads();
    }
    sc[tid] -= myc;   // exclusive (own cell only)
    __syncthreads();

    // p3: reserve global slots (one atomic per touched bucket)
    {
        int g = myc ? atomicAdd(&cursor[tid], myc) : 0;
        gb0[tid] = g;
        hist[tid] = g;   // rolling global cursor
    }
    __syncthreads();

    // p4: rank + scatter into sorted LDS order, record dest
    for (int i = tid; i < n; i += 512) {
        int b = sb[i];
        int d = atomicAdd(&hist[b], 1);       // global slot
        int pos = sc[b] + (d - gb0[b]);       // local sorted slot
        so[pos] = se[i];
        sdst[pos] = d;
    }
    __syncthreads();

    // p5: coalesced write-out (consecutive lanes -> mostly consecutive dest)
    for (int i = tid; i < n; i += 512) {
        csr[sdst[i]] = so[i];
    }
}

// ---------------- phase D: per-bucket counting sort + register accumulation --
__global__ __launch_bounds__(512) void node_sort_kernel(const ushort4* __restrict__ ub,
                                                        const float4* __restrict__ u4,
                                                        const int* __restrict__ offsets,
                                                        const uint2* __restrict__ csr,
                                                        float4* __restrict__ out4, int N) {
    __shared__ uint2 se[EDGE_CAP];        // 36.8 KB (fallback: f32 tile 32 KB)
    __shared__ int hist[BUCKET];
    __shared__ int starts[BUCKET + 1];
    __shared__ int sc[BUCKET];            // scan tmp / fallback wsum

    int b = blockIdx.x;
    int tid = threadIdx.x;
    int start = offsets[b];
    int end = offsets[b + 1];
    int cnt = end - start;

    if (tid < BUCKET) hist[tid] = 0;
    __syncthreads();

    if (cnt <= EDGE_CAP) {
        // pass 1: histogram by rowLow
        for (int i = start + tid; i < end; i += 512) {
            unsigned px = nt_load_u2(&csr[i]).x;
            atomicAdd(&hist[px >> 24], 1);
        }
        __syncthreads();
        // scan over 256 cells (threads 0..255)
        int myc = (tid < BUCKET) ? hist[tid] : 0;
        if (tid < BUCKET) sc[tid] = myc;
        __syncthreads();
        for (int off = 1; off < BUCKET; off <<= 1) {
            int v = (tid < BUCKET && tid >= off) ? sc[tid - off] : 0;
            __syncthreads();
            if (tid < BUCKET) sc[tid] += v;
            __syncthreads();
        }
        if (tid < BUCKET) {
            int excl = sc[tid] - myc;
            starts[tid] = excl;
            hist[tid] = excl;     // cursor
        }
        if (tid == BUCKET - 1) starts[BUCKET] = sc[BUCKET - 1];
        __syncthreads();
        // pass 2: scatter into sorted LDS order
        for (int i = start + tid; i < end; i += 512) {
            uint2 p = nt_load_u2(&csr[i]);
            int pos = atomicAdd(&hist[p.x >> 24], 1);
            se[pos] = p;
        }
        __syncthreads();
        // accumulate: 8 waves x 32 nodes each; 8 slots x 8 f4-lanes per wave
        int wave = tid >> 6;
        int lane = tid & 63;
        int f4 = lane & 7;
        int slot = lane >> 3;
        for (int node = wave; node < BUCKET; node += 8) {
            int s0 = starts[node];
            int s1 = starts[node + 1];
            float4 acc = make_float4(0.f, 0.f, 0.f, 0.f);
            float ws_ = 0.f;
            for (int i = s0 + slot; i < s1; i += 8) {
                uint2 p = se[i];
                int c = (int)(p.x & 0x00FFFFFFu);
                float wt = __uint_as_float(p.y);
                ushort4 us = ub[(size_t)c * 8 + f4];
                acc.x += wt * __uint_as_float((unsigned)us.x << 16);
                acc.y += wt * __uint_as_float((unsigned)us.y << 16);
                acc.z += wt * __uint_as_float((unsigned)us.z << 16);
                acc.w += wt * __uint_as_float((unsigned)us.w << 16);
                ws_ += wt;
            }
#pragma unroll
            for (int m = 8; m < 64; m <<= 1) {
                acc.x += __shfl_xor(acc.x, m, 64);
                acc.y += __shfl_xor(acc.y, m, 64);
                acc.z += __shfl_xor(acc.z, m, 64);
                acc.w += __shfl_xor(acc.w, m, 64);
                ws_   += __shfl_xor(ws_,   m, 64);
            }
            int glob = b * BUCKET + node;
            if (slot == 0 && glob < N) {
                float4 ur = nt_load_f4(&u4[(size_t)glob * 8 + f4]);
                float4 o;
                o.x = acc.x - ws_ * ur.x;
                o.y = acc.y - ws_ * ur.y;
                o.z = acc.z - ws_ * ur.z;
                o.w = acc.w - ws_ * ur.w;
                nt_store_f4(&out4[(size_t)glob * 8 + f4], o);
            }
        }
    } else {
        // oversized bucket fallback: LDS f32 tile (32 KB, overlays se)
        float* tile = (float*)se;   // 256*32 floats
        for (int i = tid; i < BUCKET * NFEAT; i += 512) tile[i] = 0.f;
        if (tid < BUCKET) sc[tid] = 0;   // wsum
        __syncthreads();
        int f4 = tid & 7;
        float* wsumf = (float*)sc;
        for (int i = start + (tid >> 3); i < end; i += 64) {
            uint2 p = nt_load_u2(&csr[i]);
            int c = (int)(p.x & 0x00FFFFFFu);
            int rl = (int)(p.x >> 24);
            float wt = __uint_as_float(p.y);
            ushort4 us = ub[(size_t)c * 8 + f4];
            float* t = &tile[rl * NFEAT + f4 * 4];
            atomicAdd(t + 0, wt * __uint_as_float((unsigned)us.x << 16));
            atomicAdd(t + 1, wt * __uint_as_float((unsigned)us.y << 16));
            atomicAdd(t + 2, wt * __uint_as_float((unsigned)us.z << 16));
            atomicAdd(t + 3, wt * __uint_as_float((unsigned)us.w << 16));
            if (f4 == 0) atomicAdd(&wsumf[rl], wt);
        }
        __syncthreads();
#pragma unroll
        for (int pass = 0; pass < 4; ++pass) {
            int idx = pass * 512 + tid;
            int node = idx >> 3;
            int ff = idx & 7;
            int glob = b * BUCKET + node;
            if (glob < N) {
                float4 ur = nt_load_f4(&u4[(size_t)glob * 8 + ff]);
                float ws_ = wsumf[node];
                const float* t = &tile[node * NFEAT + ff * 4];
                float4 o;
                o.x = t[0] - ws_ * ur.x;
                o.y = t[1] - ws_ * ur.y;
                o.z = t[2] - ws_ * ur.z;
                o.w = t[3] - ws_ * ur.w;
                nt_store_f4(&out4[(size_t)glob * 8 + ff], o);
            }
        }
    }
}

// ---------------- fallback (atomic path) ----------------

__global__ __launch_bounds__(256) void zero_out_kernel(float* __restrict__ out, int n) {
    int i = blockIdx.x * blockDim.x + threadIdx.x;
    if (i < n) out[i] = 0.0f;
}

__global__ __launch_bounds__(256) void scatter_lap_kernel(const float4* __restrict__ u4,
                                                          const float* __restrict__ w,
                                                          const int* __restrict__ row,
                                                          const int* __restrict__ col,
                                                          float* __restrict__ out, int n_edges) {
    int tid = blockIdx.x * blockDim.x + threadIdx.x;
    int e = tid >> 3;
    int f4 = tid & 7;
    if (e >= n_edges) return;
    int r = row[e];
    int c = col[e];
    float wt = w[e];
    float4 uc = u4[(size_t)c * 8 + f4];
    float4 ur = u4[(size_t)r * 8 + f4];
    float* o = out + (size_t)r * NFEAT + f4 * 4;
    atomicAdd(o + 0, wt * (uc.x - ur.x));
    atomicAdd(o + 1, wt * (uc.y - ur.y));
    atomicAdd(o + 2, wt * (uc.z - ur.z));
    atomicAdd(o + 3, wt * (uc.w - ur.w));
}

extern "C" void kernel_launch(void* const* d_in, const int* in_sizes, int n_in,
                              void* d_out, int out_size, void* d_ws, size_t ws_size,
                              hipStream_t stream) {
    const float* u = (const float*)d_in[0];
    const float* w = (const float*)d_in[1];
    const int* ei = (const int*)d_in[2];  // [2, E] int32
    float* out = (float*)d_out;

    const int E = in_sizes[1];
    const int N = out_size / NFEAT;
    const int* row = ei;
    const int* col = ei + E;

    const int NB = (N + BUCKET - 1) >> BUCKET_BITS;

    // workspace layout (256-B aligned)
    const size_t countsOff = 0;
    const size_t countsBytes = ((size_t)MAXNB * 4 + 255) & ~(size_t)255;
    const size_t offsetsOff = countsOff + countsBytes;
    const size_t offsetsBytes = ((size_t)(MAXNB + 1) * 4 + 255) & ~(size_t)255;
    const size_t cursorOff = offsetsOff + offsetsBytes;
    const size_t cursorBytes = countsBytes;
    const size_t csrOff = cursorOff + cursorBytes;
    const size_t csrBytes = ((size_t)E * 8 + 255) & ~(size_t)255;
    const size_t ubOff = csrOff + csrBytes;
    const size_t ubBytes = ((size_t)N * NFEAT * 2 + 255) & ~(size_t)255;
    const size_t totalWs = ubOff + ubBytes;

    if (ws_size < totalWs || NB > MAXNB) {
        zero_out_kernel<<<(out_size + 255) / 256, 256, 0, stream>>>(out, out_size);
        long long threads_total = (long long)E * 8;
        scatter_lap_kernel<<<(unsigned)((threads_total + 255) / 256), 256, 0, stream>>>(
            (const float4*)u, w, row, col, out, E);
        return;
    }

    char* ws = (char*)d_ws;
    int* counts = (int*)(ws + countsOff);
    int* offsets = (int*)(ws + offsetsOff);
    int* cursor = (int*)(ws + cursorOff);
    uint2* csr = (uint2*)(ws + csrOff);
    ushort4* ub = (ushort4*)(ws + ubOff);

    (void)hipMemsetAsync(counts, 0, (size_t)MAXNB * 4, stream);

    int n4 = N * (NFEAT / 4);
    convert_u_kernel<<<(n4 + 255) / 256, 256, 0, stream>>>((const float4*)u, ub, n4);

    // A: bucket histogram
    hist_kernel<<<1024, 256, 0, stream>>>(row, counts, E, NB);

    // B: single-block scan -> offsets + cursor
    scan_offsets_kernel<<<1, 512, 0, stream>>>(counts, offsets, cursor, NB);

    // C: chunk multisplit fill
    const int nChunks = (E + CH - 1) / CH;
    fill_sort_kernel<<<nChunks, 512, 0, stream>>>(row, col, w, cursor, csr, E);

    // D: per-bucket sort + accumulate
    node_sort_kernel<<<NB, 512, 0, stream>>>(ub, (const float4*)u, offsets, csr,
                                             (float4*)out, N);
}